// Round 1
// baseline (443.754 us; speedup 1.0000x reference)
//
#include <hip/hip_runtime.h>
#include <cstdint>
#include <cstddef>

typedef __bf16 bf16x8 __attribute__((ext_vector_type(8)));
typedef float f32x4 __attribute__((ext_vector_type(4)));

#define D_DIM 4096
#define NCOL 320
#define BM 32              // rows per block
#define NKT 128            // D_DIM / 32
#define EPS_F 1.1920929e-07f
#define HS 136             // padded Hg row stride (128 + 8)
#define STG 24576          // ring stage: A 4KB f32 + B 20KB bf16
#define RING 3
#define SMEM (RING * STG)  // 73728 B dynamic LDS -> 2 blocks/CU

// async global->LDS, 16B per lane; LDS dest = wave-uniform base + lane*16
__device__ __forceinline__ void gld16(const void* g, void* l) {
  __builtin_amdgcn_global_load_lds(
      (const __attribute__((address_space(1))) unsigned int*)g,
      (__attribute__((address_space(3))) unsigned int*)l,
      16, 0, 0);
}

// ---------------------------------------------------------------------------
// Pack: f32 weights -> bf16 Wp [kt][n][kk-swizzled] (16B unit u of row n at
// slot u ^ ((n>>1)&3), so main-kernel B ds_read_b128 is 2-way/free) and
// Qt [c2][n][k]. Wp row d: [dw1[d,0,:] | dw1[d,2,:] | dd[d,0:32] | dd[d,64:96]]
// ---------------------------------------------------------------------------
__global__ void dwp_pack(const float* __restrict__ dw1,
                         const float* __restrict__ qkw,
                         const float* __restrict__ dd,
                         __bf16* __restrict__ Wp,
                         __bf16* __restrict__ Qt) {
  const int b = blockIdx.x;
  const int t = threadIdx.x;
  if (b < 128) {
    __shared__ __bf16 tile[10240];   // exact linear image of Wp[kt]
    const int kt = b;
    const int kk = t >> 3;           // 0..31
    const int d = kt * 32 + kk;
    const int u = kk >> 3;
#pragma unroll
    for (int j = 0; j < 5; ++j) {
      const int n0 = ((t & 7) + j * 8) * 8;
      const float* src;
      if (n0 < 128)      src = dw1 + (size_t)d * 512 + n0;          // c=0
      else if (n0 < 256) src = dw1 + (size_t)d * 512 + 128 + n0;    // c=2
      else if (n0 < 288) src = dd + (size_t)d * 128 + (n0 - 256);   // dd 0:32
      else               src = dd + (size_t)d * 128 + (n0 - 224);   // dd 64:96
      f32x4 v0 = *(const f32x4*)src;
      f32x4 v1 = *(const f32x4*)(src + 4);
#pragma unroll
      for (int q = 0; q < 8; ++q) {
        const int n = n0 + q;
        const int pos = n * 32 + ((u ^ ((n >> 1) & 3)) << 3) + (kk & 7);
        tile[pos] = (__bf16)((q < 4) ? v0[q] : v1[q - 4]);
      }
    }
    __syncthreads();
    __bf16* dst = Wp + (size_t)kt * 10240;
#pragma unroll
    for (int k = 0; k < 5; ++k) {
      const int u16 = t + k * 256;
      *(bf16x8*)(dst + u16 * 8) = *(const bf16x8*)(tile + u16 * 8);
    }
  } else {
    // Qt: 2*128*16 16B units, gather-transpose (tiny, L2-resident)
#pragma unroll
    for (int ii = 0; ii < 16; ++ii) {
      const int q = t + ii * 256;
      const int c2 = q >> 11;
      const int rem = q & 2047;
      const int n = rem >> 4;
      const int k0 = (rem & 15) * 8;
      const float* src = qkw + (size_t)c2 * 32768 + (size_t)k0 * 128 + n;
      bf16x8 v;
#pragma unroll
      for (int j = 0; j < 8; ++j) v[j] = (__bf16)src[(size_t)j * 128];
      *(bf16x8*)(Qt + (size_t)c2 * 16384 + (size_t)n * 128 + k0) = v;
    }
  }
}

// ---------------------------------------------------------------------------
// Main fused kernel. Grid 512 x 512 threads (8 waves). BM=32 rows/block,
// 2 blocks/CU (LDS 72KB) -> 16 waves/CU (2x the 4-wave version).
// Wave w: row group rg=w>>2 (16 rows), col group cg=w&3 (80 cols, 5 tiles).
// Every thread stages 3 x gld16 per stage (24 chunks of 1KB over 8 waves):
// chunks 0..3 = A (f32, XOR-swizzled via per-lane global addr), 4..23 = B.
// Ring-3: 2 stages in flight per wave = 6 vmem ops; in-loop drain vmcnt(3).
// ---------------------------------------------------------------------------
__global__ __launch_bounds__(512, 4) void dwp_main(
    const float* __restrict__ X,
    const __bf16* __restrict__ Wp,
    const __bf16* __restrict__ Qt,
    const float* __restrict__ NS,
    float* __restrict__ Out) {
  extern __shared__ __align__(16) unsigned char lds[];
  const int t = threadIdx.x;
  const int w = t >> 6;        // 0..7
  const int l = t & 63;
  const int lq = l >> 4;
  const int lm = l & 15;
  const int m0 = blockIdx.x * BM;

  const int rg = w >> 2;       // row group: rows rg*16 .. rg*16+15
  const int cg = w & 3;        // col group: cols cg*80 .. cg*80+79
  const int cbase = cg * 80;

  // --- staging chunks: c = w*3+i; c<4 -> A chunk, else B chunk ---
  const char* gsrc[3];
  int gstep[3];
  unsigned ldsoff[3];
#pragma unroll
  for (int i = 0; i < 3; ++i) {
    const int c = w * 3 + i;
    if (c < 4) {
      // A: rows c*8 .. c*8+7, 8 x 16B units per row, XOR-swizzled in source
      const int row = c * 8 + (l >> 3);
      const int u = (l & 7) ^ (row & 7);
      gsrc[i] = (const char*)(X + (size_t)(m0 + row) * D_DIM) + u * 16;
      gstep[i] = 128;                  // 32 f32 per kt
      ldsoff[i] = (unsigned)(c * 1024);
    } else {
      const int cb = c - 4;            // 0..19
      gsrc[i] = (const char*)Wp + cb * 1024 + (size_t)l * 16;
      gstep[i] = 20480;                // 10240 bf16 per kt
      ldsoff[i] = (unsigned)(4096 + cb * 1024);
    }
  }

  // fragment offsets: A f32 (unit XOR row&7), B bf16 (unit XOR (n>>1)&3,
  // baked into Wp's global layout so staging is linear)
  unsigned aoff0, aoff1, boff[5];
  {
    const int row = rg * 16 + lm;
    aoff0 = (unsigned)(row * 128 + (((lq * 2 + 0) ^ (lm & 7)) * 16));
    aoff1 = (unsigned)(row * 128 + (((lq * 2 + 1) ^ (lm & 7)) * 16));
  }
#pragma unroll
  for (int ct = 0; ct < 5; ++ct) {
    const int n = cbase + ct * 16 + lm;
    boff[ct] = (unsigned)(4096 + n * 64 + ((lq ^ ((n >> 1) & 3)) << 4));
  }

  f32x4 acc[5];
#pragma unroll
  for (int ct = 0; ct < 5; ++ct) acc[ct] = (f32x4){0.f, 0.f, 0.f, 0.f};

  auto issue = [&](int kt, int slot) {
    unsigned char* base = lds + slot * STG;
#pragma unroll
    for (int i = 0; i < 3; ++i)
      gld16(gsrc[i] + (size_t)kt * gstep[i], base + ldsoff[i]);
  };

  auto body = [&](int kt, int slot) {
    const unsigned char* cb = lds + slot * STG;
    bf16x8 a, b[5];
    f32x4 x0 = *(const f32x4*)(cb + aoff0);
    f32x4 x1 = *(const f32x4*)(cb + aoff1);
#pragma unroll
    for (int j = 0; j < 4; ++j) {
      a[j] = (__bf16)x0[j];
      a[4 + j] = (__bf16)x1[j];
    }
#pragma unroll
    for (int ct = 0; ct < 5; ++ct) b[ct] = *(const bf16x8*)(cb + boff[ct]);
#pragma unroll
    for (int ct = 0; ct < 5; ++ct)
      acc[ct] =
          __builtin_amdgcn_mfma_f32_16x16x32_bf16(a, b[ct], acc[ct], 0, 0, 0);
  };

  issue(0, 0);
  issue(1, 1);

  // Each wave issues exactly 3 vmem ops per stage; at the in-loop wait stages
  // kt,kt+1 are outstanding (6) -> vmcnt(3) drains stage kt (FIFO). The wait
  // precedes s_barrier, so after the barrier stage kt is landed block-wide.
  int rb = 0;
  for (int kt = 0; kt < NKT - 1; ++kt) {
    asm volatile("s_waitcnt vmcnt(3)" ::: "memory");
    asm volatile("s_barrier" ::: "memory");
    if (kt + 2 < NKT) {
      int ri = rb + 2; if (ri >= RING) ri -= RING;
      issue(kt + 2, ri);
    }
    body(kt, rb);
    ++rb; if (rb == RING) rb = 0;
  }
  asm volatile("s_waitcnt vmcnt(0)" ::: "memory");
  asm volatile("s_barrier" ::: "memory");
  body(NKT - 1, rb);

  __syncthreads();  // all ring reads done before Hg overwrite

  const float ns = NS[0];

  // E1: gelu(exact) -> Hg bf16 in LDS (cols<256); tanh -> Out (dd cols)
#pragma unroll
  for (int ct = 0; ct < 5; ++ct) {
    const int ncol = cbase + ct * 16 + lm;
    const int rowb = rg * 16 + lq * 4;
    f32x4 v = acc[ct];
    if (ncol < 256) {
      const int c2 = ncol >> 7;
      const int kcol = ncol & 127;
#pragma unroll
      for (int j = 0; j < 4; ++j) {
        float x = v[j];
        float g = 0.5f * x * (1.0f + erff(x * 0.70710678118f));
        *(__bf16*)(lds + (size_t)((c2 * 32 + rowb + j) * HS + kcol) * 2) = (__bf16)g;
      }
    } else {
      const int nd = ncol - 256;
      const int off = (nd < 32) ? (128 + nd) : (256 + nd);
#pragma unroll
      for (int j = 0; j < 4; ++j)
        Out[(size_t)(m0 + rowb + j) * NCOL + off] = tanhf(v[j]);
    }
  }
  __syncthreads();

  // E2: stage-2 GEMM  W2[row][c2,i*32+m] = sum_k Hg[c2][row][k]*Qt[c2][i*32+m][k]
  // wave w: c2 = w>>2, i-group iq = w&3 (cols iq*32 .. +32, both row-tiles)
  const int c2b = w >> 2;
  const int iq = w & 3;
  const int nnb = iq * 32;
  f32x4 acc2[2][2];
#pragma unroll
  for (int rt = 0; rt < 2; ++rt)
#pragma unroll
    for (int ct = 0; ct < 2; ++ct) acc2[rt][ct] = (f32x4){0.f, 0.f, 0.f, 0.f};

#pragma unroll
  for (int ks = 0; ks < 4; ++ks) {
    bf16x8 a2[2], b2[2];
#pragma unroll
    for (int rt = 0; rt < 2; ++rt)
      a2[rt] = *(const bf16x8*)(lds +
               (size_t)((c2b * 32 + rt * 16 + lm) * HS + ks * 32 + lq * 8) * 2);
#pragma unroll
    for (int ct = 0; ct < 2; ++ct)
      b2[ct] = *(const bf16x8*)(Qt + (size_t)c2b * 16384 +
               (size_t)(nnb + ct * 16 + lm) * 128 + ks * 32 + lq * 8);
#pragma unroll
    for (int rt = 0; rt < 2; ++rt)
#pragma unroll
      for (int ct = 0; ct < 2; ++ct)
        acc2[rt][ct] =
            __builtin_amdgcn_mfma_f32_16x16x32_bf16(a2[rt], b2[ct], acc2[rt][ct], 0, 0, 0);
  }

  // E3: RMS over 32 m (i = iq), scale i>=2 by norm_scale, store f32
  const float sce = (iq >= 2) ? ns : 1.0f;
#pragma unroll
  for (int rt = 0; rt < 2; ++rt) {
    f32x4 va = acc2[rt][0];
    f32x4 vb = acc2[rt][1];
#pragma unroll
    for (int j = 0; j < 4; ++j) {
      float s = va[j] * va[j] + vb[j] * vb[j];
      s += __shfl_xor(s, 1);
      s += __shfl_xor(s, 2);
      s += __shfl_xor(s, 4);
      s += __shfl_xor(s, 8);
      const float sc = rsqrtf(s * (1.0f / 32.0f) + EPS_F) * sce;
      const size_t row = (size_t)(m0 + rt * 16 + lq * 4 + j);
      const int off = c2b * 160 + iq * 32;
      Out[row * NCOL + off + lm] = va[j] * sc;
      Out[row * NCOL + off + 16 + lm] = vb[j] * sc;
    }
  }
}

extern "C" void kernel_launch(void* const* d_in, const int* in_sizes, int n_in,
                              void* d_out, int out_size, void* d_ws, size_t ws_size,
                              hipStream_t stream) {
  const float* qv  = (const float*)d_in[0];  // (4,4096,4096) f32
  const float* dw1 = (const float*)d_in[1];  // (4096,1,4,128) f32
  const float* qkw = (const float*)d_in[2];  // (1,4,128,4,32) f32
  const float* dd  = (const float*)d_in[3];  // (4096,1,128) f32
  const float* ns  = (const float*)d_in[4];  // (1,) f32
  float* out = (float*)d_out;

  __bf16* Wp = (__bf16*)d_ws;                 // 4096*320 bf16 = 2.62 MB
  __bf16* Qt = Wp + (size_t)4096 * 320;       // 2*128*128 bf16 = 64 KB

  hipFuncSetAttribute((const void*)dwp_main,
                      hipFuncAttributeMaxDynamicSharedMemorySize, SMEM);

  dwp_pack<<<129, 256, 0, stream>>>(dw1, qkw, dd, Wp, Qt);
  dwp_main<<<512, 512, SMEM, stream>>>(qv, Wp, Qt, ns, out);
}

// Round 3
// 426.017 us; speedup vs baseline: 1.0416x; 1.0416x over previous
//
#include <hip/hip_runtime.h>
#include <cstdint>
#include <cstddef>

typedef __bf16 bf16x8 __attribute__((ext_vector_type(8)));
typedef float f32x4 __attribute__((ext_vector_type(4)));

#define D_DIM 4096
#define NCOL 320
#define BM 64              // rows per block
#define NKT 128            // D_DIM / 32
#define EPS_F 1.1920929e-07f
#define HS 136             // padded Hg row stride (128 + 8)
#define ABYTES 8192        // A region: 64 rows x 128 B
#define STG 28672          // ring stage: A 8KB f32 + B 20KB bf16
#define RING 4
#define SMEM (RING * STG)  // 114688 B dynamic LDS -> 1 block/CU, 16 waves

// async global->LDS, 16B per lane; LDS dest = wave-uniform base + lane*16
__device__ __forceinline__ void gld16(const void* g, void* l) {
  __builtin_amdgcn_global_load_lds(
      (const __attribute__((address_space(1))) unsigned int*)g,
      (__attribute__((address_space(3))) unsigned int*)l,
      16, 0, 0);
}

// ---------------------------------------------------------------------------
// Pack: f32 weights -> bf16 Wp [kt][n][kk-swizzled] (16B unit u of row n at
// slot u ^ ((n>>1)&3), so main-kernel B ds_read_b128 is 2-way/free) and
// Qt [c2][n][k]. Wp row d: [dw1[d,0,:] | dw1[d,2,:] | dd[d,0:32] | dd[d,64:96]]
// ---------------------------------------------------------------------------
__global__ void dwp_pack(const float* __restrict__ dw1,
                         const float* __restrict__ qkw,
                         const float* __restrict__ dd,
                         __bf16* __restrict__ Wp,
                         __bf16* __restrict__ Qt) {
  const int b = blockIdx.x;
  const int t = threadIdx.x;
  if (b < 128) {
    __shared__ __bf16 tile[10240];   // exact linear image of Wp[kt]
    const int kt = b;
    const int kk = t >> 3;           // 0..31
    const int d = kt * 32 + kk;
    const int u = kk >> 3;
#pragma unroll
    for (int j = 0; j < 5; ++j) {
      const int n0 = ((t & 7) + j * 8) * 8;
      const float* src;
      if (n0 < 128)      src = dw1 + (size_t)d * 512 + n0;          // c=0
      else if (n0 < 256) src = dw1 + (size_t)d * 512 + 128 + n0;    // c=2
      else if (n0 < 288) src = dd + (size_t)d * 128 + (n0 - 256);   // dd 0:32
      else               src = dd + (size_t)d * 128 + (n0 - 224);   // dd 64:96
      f32x4 v0 = *(const f32x4*)src;
      f32x4 v1 = *(const f32x4*)(src + 4);
#pragma unroll
      for (int q = 0; q < 8; ++q) {
        const int n = n0 + q;
        const int pos = n * 32 + ((u ^ ((n >> 1) & 3)) << 3) + (kk & 7);
        tile[pos] = (__bf16)((q < 4) ? v0[q] : v1[q - 4]);
      }
    }
    __syncthreads();
    __bf16* dst = Wp + (size_t)kt * 10240;
#pragma unroll
    for (int k = 0; k < 5; ++k) {
      const int u16 = t + k * 256;
      *(bf16x8*)(dst + u16 * 8) = *(const bf16x8*)(tile + u16 * 8);
    }
  } else {
    // Qt: 2*128*16 16B units, gather-transpose (tiny, L2-resident)
#pragma unroll
    for (int ii = 0; ii < 16; ++ii) {
      const int q = t + ii * 256;
      const int c2 = q >> 11;
      const int rem = q & 2047;
      const int n = rem >> 4;
      const int k0 = (rem & 15) * 8;
      const float* src = qkw + (size_t)c2 * 32768 + (size_t)k0 * 128 + n;
      bf16x8 v;
#pragma unroll
      for (int j = 0; j < 8; ++j) v[j] = (__bf16)src[(size_t)j * 128];
      *(bf16x8*)(Qt + (size_t)c2 * 16384 + (size_t)n * 128 + k0) = v;
    }
  }
}

// ---------------------------------------------------------------------------
// Main fused kernel. Grid 256 x 1024 threads (16 waves), BM=64 rows/block ->
// 1 block/CU. B (Wp) traffic halves vs BM=32: total staged bytes 1.6GB->0.93GB
// (the VMEM port is the saturated resource; occupancy-doubling was a no-op).
// Wave w: row group rg=w>>2 (16 rows), col group cg=w&3 (80 cols, 5 tiles).
// Staging: 28 chunks of 1KB per stage (8 A + 20 B); wave w issues chunks
// {w, w+16<28} -> waves 0-11 issue 2 gld16/stage, waves 12-15 issue 1.
// Ring-4, prefetch depth 3; stage kt lives in slot kt&3. NO stage >= NKT is
// ever issued (the R2 crash: unguarded issue(128) read past the end of X).
// ---------------------------------------------------------------------------
__global__ __launch_bounds__(1024, 4) void dwp_main(
    const float* __restrict__ X,
    const __bf16* __restrict__ Wp,
    const __bf16* __restrict__ Qt,
    const float* __restrict__ NS,
    float* __restrict__ Out) {
  extern __shared__ __align__(16) unsigned char lds[];
  const int t = threadIdx.x;
  const int w = t >> 6;        // 0..15
  const int l = t & 63;
  const int lq = l >> 4;
  const int lm = l & 15;
  const int m0 = blockIdx.x * BM;

  const int rg = w >> 2;       // row group: rows rg*16 .. rg*16+15
  const int cg = w & 3;        // col group: cols cg*80 .. cg*80+79
  const int cbase = cg * 80;

  // --- staging chunks: c = w + i*16; c<8 -> A chunk, else B chunk cb=c-8 ---
  const int cnt = (w < 12) ? 2 : 1;
  const char* gsrc[2];
  int gstep[2];
  unsigned ldsoff[2];
#pragma unroll
  for (int i = 0; i < 2; ++i) {
    const int c = w + i * 16;
    if (i < cnt && c < 8) {
      // A: rows c*8 .. c*8+7, 8 x 16B units per row, XOR-swizzled in source
      const int row = c * 8 + (l >> 3);
      const int u = (l & 7) ^ (row & 7);
      gsrc[i] = (const char*)(X + (size_t)(m0 + row) * D_DIM) + u * 16;
      gstep[i] = 128;                  // 32 f32 per kt
      ldsoff[i] = (unsigned)(c * 1024);
    } else if (i < cnt) {
      const int cb = c - 8;            // 0..19
      gsrc[i] = (const char*)Wp + cb * 1024 + (size_t)l * 16;
      gstep[i] = 20480;                // 10240 bf16 per kt
      ldsoff[i] = (unsigned)(ABYTES + cb * 1024);
    } else {
      gsrc[i] = nullptr; gstep[i] = 0; ldsoff[i] = 0;
    }
  }

  // fragment offsets: A f32 (unit XOR row&7), B bf16 (unit XOR (n>>1)&3,
  // baked into Wp's global layout so staging is linear)
  unsigned aoff0, aoff1, boff[5];
  {
    const int row = rg * 16 + lm;
    aoff0 = (unsigned)(row * 128 + (((lq * 2 + 0) ^ (lm & 7)) * 16));
    aoff1 = (unsigned)(row * 128 + (((lq * 2 + 1) ^ (lm & 7)) * 16));
  }
#pragma unroll
  for (int ct = 0; ct < 5; ++ct) {
    const int n = cbase + ct * 16 + lm;
    boff[ct] = (unsigned)(ABYTES + n * 64 + ((lq ^ ((n >> 1) & 3)) << 4));
  }

  f32x4 acc[5];
#pragma unroll
  for (int ct = 0; ct < 5; ++ct) acc[ct] = (f32x4){0.f, 0.f, 0.f, 0.f};

  auto issue = [&](int kt, int slot) {
    unsigned char* base = lds + slot * STG;
#pragma unroll
    for (int i = 0; i < 2; ++i)
      if (i < cnt)
        gld16(gsrc[i] + (size_t)kt * gstep[i], base + ldsoff[i]);
  };

  auto body = [&](int kt, int slot) {
    const unsigned char* cb = lds + slot * STG;
    bf16x8 a, b[5];
    f32x4 x0 = *(const f32x4*)(cb + aoff0);
    f32x4 x1 = *(const f32x4*)(cb + aoff1);
#pragma unroll
    for (int j = 0; j < 4; ++j) {
      a[j] = (__bf16)x0[j];
      a[4 + j] = (__bf16)x1[j];
    }
#pragma unroll
    for (int ct = 0; ct < 5; ++ct) b[ct] = *(const bf16x8*)(cb + boff[ct]);
#pragma unroll
    for (int ct = 0; ct < 5; ++ct)
      acc[ct] =
          __builtin_amdgcn_mfma_f32_16x16x32_bf16(a, b[ct], acc[ct], 0, 0, 0);
  };

  issue(0, 0);
  issue(1, 1);
  issue(2, 2);

  // Per-wave counted waits: wave issues cnt vmem/stage; stages kt..kt+2 in
  // flight at the in-loop wait -> vmcnt(2*cnt) drains exactly stage kt (FIFO).
  // The wait precedes s_barrier, so after the barrier stage kt is landed
  // block-wide. Tail (last 3 stages): no new issues, counted waits step down
  // 2*cnt -> cnt -> 0 so each body's stage is drained before its barrier.
  for (int kt = 0; kt < NKT - 3; ++kt) {
    if (w < 12) asm volatile("s_waitcnt vmcnt(4)" ::: "memory");
    else        asm volatile("s_waitcnt vmcnt(2)" ::: "memory");
    asm volatile("s_barrier" ::: "memory");
    issue(kt + 3, (kt + 3) & 3);
    body(kt, kt & 3);
  }
  // kt = NKT-3: stages NKT-3..NKT-1 outstanding (3), nothing left to issue
  if (w < 12) asm volatile("s_waitcnt vmcnt(4)" ::: "memory");
  else        asm volatile("s_waitcnt vmcnt(2)" ::: "memory");
  asm volatile("s_barrier" ::: "memory");
  body(NKT - 3, (NKT - 3) & 3);
  // kt = NKT-2: stages NKT-2..NKT-1 outstanding (2)
  if (w < 12) asm volatile("s_waitcnt vmcnt(2)" ::: "memory");
  else        asm volatile("s_waitcnt vmcnt(1)" ::: "memory");
  asm volatile("s_barrier" ::: "memory");
  body(NKT - 2, (NKT - 2) & 3);
  // kt = NKT-1: last stage
  asm volatile("s_waitcnt vmcnt(0)" ::: "memory");
  asm volatile("s_barrier" ::: "memory");
  body(NKT - 1, (NKT - 1) & 3);

  __syncthreads();  // all ring reads done before Hg overwrite

  const float ns = NS[0];

  // E1: gelu(exact) -> Hg bf16 in LDS (cols<256); tanh -> Out (dd cols)
#pragma unroll
  for (int ct = 0; ct < 5; ++ct) {
    const int ncol = cbase + ct * 16 + lm;
    const int rowb = rg * 16 + lq * 4;
    f32x4 v = acc[ct];
    if (ncol < 256) {
      const int c2 = ncol >> 7;
      const int kcol = ncol & 127;
#pragma unroll
      for (int j = 0; j < 4; ++j) {
        float x = v[j];
        float g = 0.5f * x * (1.0f + erff(x * 0.70710678118f));
        *(__bf16*)(lds + (size_t)((c2 * 64 + rowb + j) * HS + kcol) * 2) = (__bf16)g;
      }
    } else {
      const int nd = ncol - 256;
      const int off = (nd < 32) ? (128 + nd) : (256 + nd);
#pragma unroll
      for (int j = 0; j < 4; ++j)
        Out[(size_t)(m0 + rowb + j) * NCOL + off] = tanhf(v[j]);
    }
  }
  __syncthreads();

  // E2: stage-2 GEMM  W2[row][c2,i*32+m] = sum_k Hg[c2][row][k]*Qt[c2][i*32+m][k]
  // wave w: c2 = w>>3, i-group iq = (w>>1)&3, row half rh = w&1 (32 rows)
  const int c2b = w >> 3;
  const int iq = (w >> 1) & 3;
  const int rh = w & 1;
  const int nnb = iq * 32;
  f32x4 acc2[2][2];
#pragma unroll
  for (int rt = 0; rt < 2; ++rt)
#pragma unroll
    for (int ct = 0; ct < 2; ++ct) acc2[rt][ct] = (f32x4){0.f, 0.f, 0.f, 0.f};

#pragma unroll
  for (int ks = 0; ks < 4; ++ks) {
    bf16x8 a2[2], b2[2];
#pragma unroll
    for (int rt = 0; rt < 2; ++rt)
      a2[rt] = *(const bf16x8*)(lds +
               (size_t)((c2b * 64 + rh * 32 + rt * 16 + lm) * HS + ks * 32 + lq * 8) * 2);
#pragma unroll
    for (int ct = 0; ct < 2; ++ct)
      b2[ct] = *(const bf16x8*)(Qt + (size_t)c2b * 16384 +
               (size_t)(nnb + ct * 16 + lm) * 128 + ks * 32 + lq * 8);
#pragma unroll
    for (int rt = 0; rt < 2; ++rt)
#pragma unroll
      for (int ct = 0; ct < 2; ++ct)
        acc2[rt][ct] =
            __builtin_amdgcn_mfma_f32_16x16x32_bf16(a2[rt], b2[ct], acc2[rt][ct], 0, 0, 0);
  }

  // E3: RMS over 32 m (i = iq), scale i>=2 by norm_scale, store f32
  const float sce = (iq >= 2) ? ns : 1.0f;
#pragma unroll
  for (int rt = 0; rt < 2; ++rt) {
    f32x4 va = acc2[rt][0];
    f32x4 vb = acc2[rt][1];
#pragma unroll
    for (int j = 0; j < 4; ++j) {
      float s = va[j] * va[j] + vb[j] * vb[j];
      s += __shfl_xor(s, 1);
      s += __shfl_xor(s, 2);
      s += __shfl_xor(s, 4);
      s += __shfl_xor(s, 8);
      const float sc = rsqrtf(s * (1.0f / 32.0f) + EPS_F) * sce;
      const size_t row = (size_t)(m0 + rh * 32 + rt * 16 + lq * 4 + j);
      const int off = c2b * 160 + iq * 32;
      Out[row * NCOL + off + lm] = va[j] * sc;
      Out[row * NCOL + off + 16 + lm] = vb[j] * sc;
    }
  }
}

extern "C" void kernel_launch(void* const* d_in, const int* in_sizes, int n_in,
                              void* d_out, int out_size, void* d_ws, size_t ws_size,
                              hipStream_t stream) {
  const float* qv  = (const float*)d_in[0];  // (4,4096,4096) f32
  const float* dw1 = (const float*)d_in[1];  // (4096,1,4,128) f32
  const float* qkw = (const float*)d_in[2];  // (1,4,128,4,32) f32
  const float* dd  = (const float*)d_in[3];  // (4096,1,128) f32
  const float* ns  = (const float*)d_in[4];  // (1,) f32
  float* out = (float*)d_out;

  __bf16* Wp = (__bf16*)d_ws;                 // 4096*320 bf16 = 2.62 MB
  __bf16* Qt = Wp + (size_t)4096 * 320;       // 2*128*128 bf16 = 64 KB

  hipFuncSetAttribute((const void*)dwp_main,
                      hipFuncAttributeMaxDynamicSharedMemorySize, SMEM);

  dwp_pack<<<129, 256, 0, stream>>>(dw1, qkw, dd, Wp, Qt);
  dwp_main<<<256, 1024, SMEM, stream>>>(qv, Wp, Qt, ns, out);
}